// Round 9
// baseline (159.313 us; speedup 1.0000x reference)
//
#include <hip/hip_runtime.h>

#define NB 64
#define NS 512
#define ND 768
#define NT 4
#define NC 10
#define NEG (-1e30f)

// ---------------------------------------------------------------------------
// Single kernel, 1024 blocks x 256 threads (4 blocks/CU, 16 waves/CU).
// Phase 1: each block computes logits for 32 tokens (16 blocks per batch).
//   W_eff stored TRANSPOSED in LDS (wt[t][d]) -> 2-way-aliased broadcast
//   reads, no 8-way bank conflict. 16 lanes per token, 2 tokens per group.
// Tail: __threadfence + device atomicAdd(cnt[b]); the last block of each
//   batch runs the chunk-parallel CRF scan (r2 structure, proven absmax 0).
//   LDS overlaid via union (phase 1 W vs phase 2 tree buffers).
// ---------------------------------------------------------------------------
__global__ __launch_bounds__(256) void fused_kernel(
    const int* __restrict__ words, const int* __restrict__ target,
    const int* __restrict__ corpus, const float* __restrict__ embed,
    const float* __restrict__ sW, const float* __restrict__ sb,
    const float* __restrict__ dA, const float* __restrict__ db,
    const float* __restrict__ trans, const float* __restrict__ start_s,
    const float* __restrict__ end_s, float* __restrict__ logits,
    int* __restrict__ cnt, float* __restrict__ out)
{
  __shared__ union {
    struct {
      float wt[NT][ND];   // 12288 B, transposed W_eff
      float4 bl;
    } p1;
    struct {
      float bufA[64][16];
      float bufB[32][16];
      float wg[4];
      int   wc[4];
    } p2;
  } U;
  __shared__ int lastFlag;

  const int tid = threadIdx.x;
  const int blk = blockIdx.x;
  const int b = blk >> 4;          // 16 blocks per batch

  // ======================= phase 1: logits (32 tokens) =======================
  {
    const int c = __builtin_amdgcn_readfirstlane(corpus[b]);
    const float4* sW4 = (const float4*)sW;
    const float4* dA4 = ((const float4*)dA) + (size_t)c * ND;
#pragma unroll
    for (int k = 0; k < 3; ++k) {
      const int d = tid + k * 256;
      const float4 a = sW4[d];     // a.{x,y,z,w} = W[d][t=0..3]
      const float4 e = dA4[d];
      U.p1.wt[0][d] = a.x + e.x;
      U.p1.wt[1][d] = a.y + e.y;
      U.p1.wt[2][d] = a.z + e.z;
      U.p1.wt[3][d] = a.w + e.w;
    }
    if (tid == 0) {
      const float4 a = *(const float4*)sb;
      const float4 e = ((const float4*)db)[c];
      U.p1.bl = make_float4(a.x + e.x, a.y + e.y, a.z + e.z, a.w + e.w);
    }
    __syncthreads();

    const int grp = tid >> 4;       // 0..15
    const int q   = tid & 15;
    const int gA  = blk * 32 + grp * 2;
    const int gB  = gA + 1;

    const float4* __restrict__ rowA = (const float4*)(embed + (size_t)words[gA] * ND);
    const float4* __restrict__ rowB = (const float4*)(embed + (size_t)words[gB] * ND);
    const float4* __restrict__ Wt4 = (const float4*)&U.p1.wt[0][0];

    float a0 = 0.f, a1 = 0.f, a2 = 0.f, a3 = 0.f;
    float b0 = 0.f, b1 = 0.f, b2 = 0.f, b3 = 0.f;
#pragma unroll
    for (int i = 0; i < 12; ++i) {
      const float4 xa = rowA[i * 16 + q];
      const float4 xb = rowB[i * 16 + q];
      const float4 w0 = Wt4[0 * 192 + i * 16 + q];
      const float4 w1 = Wt4[1 * 192 + i * 16 + q];
      const float4 w2 = Wt4[2 * 192 + i * 16 + q];
      const float4 w3 = Wt4[3 * 192 + i * 16 + q];
      a0 = fmaf(xa.x, w0.x, a0); a0 = fmaf(xa.y, w0.y, a0);
      a0 = fmaf(xa.z, w0.z, a0); a0 = fmaf(xa.w, w0.w, a0);
      a1 = fmaf(xa.x, w1.x, a1); a1 = fmaf(xa.y, w1.y, a1);
      a1 = fmaf(xa.z, w1.z, a1); a1 = fmaf(xa.w, w1.w, a1);
      a2 = fmaf(xa.x, w2.x, a2); a2 = fmaf(xa.y, w2.y, a2);
      a2 = fmaf(xa.z, w2.z, a2); a2 = fmaf(xa.w, w2.w, a2);
      a3 = fmaf(xa.x, w3.x, a3); a3 = fmaf(xa.y, w3.y, a3);
      a3 = fmaf(xa.z, w3.z, a3); a3 = fmaf(xa.w, w3.w, a3);
      b0 = fmaf(xb.x, w0.x, b0); b0 = fmaf(xb.y, w0.y, b0);
      b0 = fmaf(xb.z, w0.z, b0); b0 = fmaf(xb.w, w0.w, b0);
      b1 = fmaf(xb.x, w1.x, b1); b1 = fmaf(xb.y, w1.y, b1);
      b1 = fmaf(xb.z, w1.z, b1); b1 = fmaf(xb.w, w1.w, b1);
      b2 = fmaf(xb.x, w2.x, b2); b2 = fmaf(xb.y, w2.y, b2);
      b2 = fmaf(xb.z, w2.z, b2); b2 = fmaf(xb.w, w2.w, b2);
      b3 = fmaf(xb.x, w3.x, b3); b3 = fmaf(xb.y, w3.y, b3);
      b3 = fmaf(xb.z, w3.z, b3); b3 = fmaf(xb.w, w3.w, b3);
    }

#pragma unroll
    for (int off = 8; off; off >>= 1) {
      a0 += __shfl_xor(a0, off); a1 += __shfl_xor(a1, off);
      a2 += __shfl_xor(a2, off); a3 += __shfl_xor(a3, off);
      b0 += __shfl_xor(b0, off); b1 += __shfl_xor(b1, off);
      b2 += __shfl_xor(b2, off); b3 += __shfl_xor(b3, off);
    }

    if (q < 2) {
      float s0 = (q == 0) ? a0 : b0;
      float s1 = (q == 0) ? a1 : b1;
      float s2 = (q == 0) ? a2 : b2;
      float s3 = (q == 0) ? a3 : b3;
      const float4 bl = U.p1.bl;
      s0 += bl.x; s1 += bl.y; s2 += bl.z; s3 += bl.w;
      const float m = fmaxf(fmaxf(s0, s1), fmaxf(s2, s3));
      const float sum = __expf(s0 - m) + __expf(s1 - m) +
                        __expf(s2 - m) + __expf(s3 - m);
      const float lse = m + __logf(sum);
      ((float4*)logits)[gA + q] = make_float4(s0 - lse, s1 - lse, s2 - lse, s3 - lse);
    }
  }

  // -------- release our writes, count; only the last block continues --------
  __threadfence();
  __syncthreads();
  if (tid == 0) {
    const int old = atomicAdd(&cnt[b], 1);
    lastFlag = (old == 15);
  }
  __syncthreads();
  if (!lastFlag) return;
  __threadfence();   // acquire: make all 16 blocks' logits visible
  __syncthreads();   // LDS overlay safety (p1 -> p2)

  // ======================= phase 2: CRF for batch b =======================
  {
    const int cc = tid >> 2;   // chunk 0..63
    const int a  = tid & 3;    // basis row

    const float* lg = logits + (size_t)b * NS * NT;
    const int* wb = words + b * NS;
    const int* tb = target + b * NS;

    // ---- gold partials: positions 2*tid, 2*tid+1 ----
    float gp = 0.f; int cp = 0;
#pragma unroll
    for (int qq = 0; qq < 2; ++qq) {
      const int s = tid * 2 + qq;
      if (wb[s] != 0) {
        const int t = tb[s];
        gp += lg[s * 4 + t];
        if (s > 0) gp += trans[tb[s - 1] * 4 + t];
        ++cp;
      }
    }
#pragma unroll
    for (int off = 32; off; off >>= 1) {
      gp += __shfl_xor(gp, off);
      cp += __shfl_xor(cp, off);
    }
    if ((tid & 63) == 0) { U.p2.wg[tid >> 6] = gp; U.p2.wc[tid >> 6] = cp; }

    // ---- phase A: 8-step chunk recursion ----
    float T[4][4];
#pragma unroll
    for (int i = 0; i < 4; ++i)
#pragma unroll
      for (int j = 0; j < 4; ++j) T[i][j] = trans[i * 4 + j];

    const int s_beg = 1 + cc * 8;   // chunks cover s = 1..511
    float4 lv[8]; int wm[8];
#pragma unroll
    for (int qq = 0; qq < 8; ++qq) {
      const int s = s_beg + qq;
      const bool in = s < NS;
      wm[qq] = in ? wb[s] : 0;
      lv[qq] = in ? *(const float4*)(lg + s * 4) : make_float4(0.f, 0.f, 0.f, 0.f);
    }

    float v0 = (a == 0) ? 0.f : NEG;
    float v1 = (a == 1) ? 0.f : NEG;
    float v2 = (a == 2) ? 0.f : NEG;
    float v3 = (a == 3) ? 0.f : NEG;
#pragma unroll
    for (int qq = 0; qq < 8; ++qq) {
      if (wm[qq] != 0) {
        const float4 l = lv[qq];
        float t0, t1, t2, t3, m, sm;
        float n0, n1, n2, n3;
        t0 = v0 + T[0][0]; t1 = v1 + T[1][0]; t2 = v2 + T[2][0]; t3 = v3 + T[3][0];
        m = fmaxf(fmaxf(t0, t1), fmaxf(t2, t3));
        sm = __expf(t0 - m) + __expf(t1 - m) + __expf(t2 - m) + __expf(t3 - m);
        n0 = m + __logf(sm) + l.x;
        t0 = v0 + T[0][1]; t1 = v1 + T[1][1]; t2 = v2 + T[2][1]; t3 = v3 + T[3][1];
        m = fmaxf(fmaxf(t0, t1), fmaxf(t2, t3));
        sm = __expf(t0 - m) + __expf(t1 - m) + __expf(t2 - m) + __expf(t3 - m);
        n1 = m + __logf(sm) + l.y;
        t0 = v0 + T[0][2]; t1 = v1 + T[1][2]; t2 = v2 + T[2][2]; t3 = v3 + T[3][2];
        m = fmaxf(fmaxf(t0, t1), fmaxf(t2, t3));
        sm = __expf(t0 - m) + __expf(t1 - m) + __expf(t2 - m) + __expf(t3 - m);
        n2 = m + __logf(sm) + l.z;
        t0 = v0 + T[0][3]; t1 = v1 + T[1][3]; t2 = v2 + T[2][3]; t3 = v3 + T[3][3];
        m = fmaxf(fmaxf(t0, t1), fmaxf(t2, t3));
        sm = __expf(t0 - m) + __expf(t1 - m) + __expf(t2 - m) + __expf(t3 - m);
        n3 = m + __logf(sm) + l.w;
        v0 = n0; v1 = n1; v2 = n2; v3 = n3;
      }
    }
    U.p2.bufA[cc][a * 4 + 0] = v0;
    U.p2.bufA[cc][a * 4 + 1] = v1;
    U.p2.bufA[cc][a * 4 + 2] = v2;
    U.p2.bufA[cc][a * 4 + 3] = v3;

    // ---- phase B: 6-level pairwise tree ----
    float* src = &U.p2.bufA[0][0];
    float* dst = &U.p2.bufB[0][0];
    for (int n = 64; n > 1; n >>= 1) {
      const int entries = (n >> 1) * 16;
      __syncthreads();
      for (int e = tid; e < entries; e += 256) {
        const int p = e >> 4;
        const int aa = (e >> 2) & 3;
        const int jj = e & 3;
        const float* C1 = src + (2 * p) * 16;
        const float* C2 = src + (2 * p + 1) * 16;
        const float t0 = C1[aa * 4 + 0] + C2[0 * 4 + jj];
        const float t1 = C1[aa * 4 + 1] + C2[1 * 4 + jj];
        const float t2 = C1[aa * 4 + 2] + C2[2 * 4 + jj];
        const float t3 = C1[aa * 4 + 3] + C2[3 * 4 + jj];
        const float m = fmaxf(fmaxf(t0, t1), fmaxf(t2, t3));
        dst[p * 16 + aa * 4 + jj] =
            m + __logf(__expf(t0 - m) + __expf(t1 - m) +
                       __expf(t2 - m) + __expf(t3 - m));
      }
      float* tmp = src; src = dst; dst = tmp;
    }
    __syncthreads();
    // after 6 swaps the final matrix is back in bufA

    if (tid == 0) {
      const float* C = &U.p2.bufA[0][0];
      const float4 l0 = *(const float4*)lg;
      const float a0 = l0.x + start_s[0];
      const float a1 = l0.y + start_s[1];
      const float a2 = l0.z + start_s[2];
      const float a3 = l0.w + start_s[3];
      float af[4];
#pragma unroll
      for (int j = 0; j < 4; ++j) {
        const float t0 = a0 + C[0 * 4 + j];
        const float t1 = a1 + C[1 * 4 + j];
        const float t2 = a2 + C[2 * 4 + j];
        const float t3 = a3 + C[3 * 4 + j];
        const float m = fmaxf(fmaxf(t0, t1), fmaxf(t2, t3));
        af[j] = m + __logf(__expf(t0 - m) + __expf(t1 - m) +
                           __expf(t2 - m) + __expf(t3 - m));
      }
      const float z0 = af[0] + end_s[0], z1 = af[1] + end_s[1];
      const float z2 = af[2] + end_s[2], z3 = af[3] + end_s[3];
      const float mz = fmaxf(fmaxf(z0, z1), fmaxf(z2, z3));
      const float norm = mz + __logf(__expf(z0 - mz) + __expf(z1 - mz) +
                                     __expf(z2 - mz) + __expf(z3 - mz));

      float gold = U.p2.wg[0] + U.p2.wg[1] + U.p2.wg[2] + U.p2.wg[3];
      const int cnt4 = U.p2.wc[0] + U.p2.wc[1] + U.p2.wc[2] + U.p2.wc[3];
      const int last = (cnt4 - 1) > 0 ? (cnt4 - 1) : 0;
      gold += start_s[tb[0]] + end_s[tb[last]];
      out[b] = norm - gold;
    }
  }
}

extern "C" void kernel_launch(void* const* d_in, const int* in_sizes, int n_in,
                              void* d_out, int out_size, void* d_ws, size_t ws_size,
                              hipStream_t stream) {
  const int*   words   = (const int*)d_in[0];
  const int*   target  = (const int*)d_in[1];
  const int*   corpus  = (const int*)d_in[2];
  const float* embed   = (const float*)d_in[3];
  const float* sW      = (const float*)d_in[4];
  const float* sb      = (const float*)d_in[5];
  const float* dA      = (const float*)d_in[6];
  const float* db      = (const float*)d_in[7];
  const float* trans   = (const float*)d_in[8];
  const float* start_s = (const float*)d_in[9];
  const float* end_s   = (const float*)d_in[10];
  float* out = (float*)d_out;

  float* logits = (float*)d_ws;                 // NB*NS*NT floats = 512 KB
  int*   cnt    = (int*)(logits + (size_t)NB * NS * NT);  // NB ints

  hipMemsetAsync(cnt, 0, NB * sizeof(int), stream);
  fused_kernel<<<NB * 16, 256, 0, stream>>>(words, target, corpus, embed, sW, sb,
                                            dA, db, trans, start_s, end_s,
                                            logits, cnt, out);
}

// Round 10
// 33.685 us; speedup vs baseline: 4.7294x; 4.7294x over previous
//
#include <hip/hip_runtime.h>

#define NB 64
#define NS 512
#define ND 768
#define NT 4
#define NC 10
#define NEG (-1e30f)

// ---------------------------------------------------------------------------
// Kernel 1: logits (gather+proj+log_softmax) + CRF phase A + gold partials.
// 2048 blocks x 256 threads; 16 tokens/block (16 lanes per token), 32
// blocks/batch. Weights transposed in LDS (wt[t][d]) -> 2-way alias = free
// (r9 counters: conflicts 1.2M -> 8K). Block-local extras:
//   wave0 lanes 0..15 : gold partial for its 16 positions -> partG/partC
//   wave1 lanes 0..7  : two 8-step chunk recursions -> chunkM (128 B)
// No global logits buffer at all.
// ---------------------------------------------------------------------------
__global__ __launch_bounds__(256) void logits_phaseA_kernel(
    const int* __restrict__ words, const int* __restrict__ target,
    const int* __restrict__ corpus, const float* __restrict__ embed,
    const float* __restrict__ sW, const float* __restrict__ sb,
    const float* __restrict__ dA, const float* __restrict__ db,
    const float* __restrict__ trans,
    float4* __restrict__ chunkM,   // [NB*64*4]  (b*64+c)*4 + a
    float*  __restrict__ partG,    // [NB*32]
    int*    __restrict__ partC,    // [NB*32]
    float4* __restrict__ l0ws)     // [NB]
{
  __shared__ float wt[NT][ND];   // transposed W_eff
  __shared__ float4 bl;
  __shared__ float4 lsm[16];     // this block's 16 log-softmaxed logits

  const int tid = threadIdx.x;
  const int blk = blockIdx.x;
  const int b = blk >> 5;        // 32 blocks/batch
  const int j = blk & 31;        // block within batch (tokens j*16..j*16+15)

  const int c = __builtin_amdgcn_readfirstlane(corpus[b]);
  const float4* sW4 = (const float4*)sW;
  const float4* dA4 = ((const float4*)dA) + (size_t)c * ND;
#pragma unroll
  for (int k = 0; k < 3; ++k) {
    const int d = tid + k * 256;
    const float4 a = sW4[d];     // W[d][0..3]
    const float4 e = dA4[d];
    wt[0][d] = a.x + e.x;
    wt[1][d] = a.y + e.y;
    wt[2][d] = a.z + e.z;
    wt[3][d] = a.w + e.w;
  }
  if (tid == 0) {
    const float4 a = *(const float4*)sb;
    const float4 e = ((const float4*)db)[c];
    bl = make_float4(a.x + e.x, a.y + e.y, a.z + e.z, a.w + e.w);
  }
  __syncthreads();

  const int grp = tid >> 4;      // 0..15: token group
  const int q   = tid & 15;
  const int g   = blk * 16 + grp;

  const float4* __restrict__ row4 = (const float4*)(embed + (size_t)words[g] * ND);
  const float4* __restrict__ Wt4 = (const float4*)&wt[0][0];

  // prefetch the whole row slice (12 independent HBM loads in flight)
  float4 x[12];
#pragma unroll
  for (int i = 0; i < 12; ++i) x[i] = row4[i * 16 + q];

  float a0 = 0.f, a1 = 0.f, a2 = 0.f, a3 = 0.f;
#pragma unroll
  for (int i = 0; i < 12; ++i) {
    const float4 w0 = Wt4[0 * 192 + i * 16 + q];   // banks q*4.. -> 2-way, free
    const float4 w1 = Wt4[1 * 192 + i * 16 + q];
    const float4 w2 = Wt4[2 * 192 + i * 16 + q];
    const float4 w3 = Wt4[3 * 192 + i * 16 + q];
    a0 = fmaf(x[i].x, w0.x, a0); a0 = fmaf(x[i].y, w0.y, a0);
    a0 = fmaf(x[i].z, w0.z, a0); a0 = fmaf(x[i].w, w0.w, a0);
    a1 = fmaf(x[i].x, w1.x, a1); a1 = fmaf(x[i].y, w1.y, a1);
    a1 = fmaf(x[i].z, w1.z, a1); a1 = fmaf(x[i].w, w1.w, a1);
    a2 = fmaf(x[i].x, w2.x, a2); a2 = fmaf(x[i].y, w2.y, a2);
    a2 = fmaf(x[i].z, w2.z, a2); a2 = fmaf(x[i].w, w2.w, a2);
    a3 = fmaf(x[i].x, w3.x, a3); a3 = fmaf(x[i].y, w3.y, a3);
    a3 = fmaf(x[i].z, w3.z, a3); a3 = fmaf(x[i].w, w3.w, a3);
  }

#pragma unroll
  for (int off = 8; off; off >>= 1) {
    a0 += __shfl_xor(a0, off, 16);
    a1 += __shfl_xor(a1, off, 16);
    a2 += __shfl_xor(a2, off, 16);
    a3 += __shfl_xor(a3, off, 16);
  }

  if (q == 0) {
    a0 += bl.x; a1 += bl.y; a2 += bl.z; a3 += bl.w;
    const float m = fmaxf(fmaxf(a0, a1), fmaxf(a2, a3));
    const float sum = __expf(a0 - m) + __expf(a1 - m) +
                      __expf(a2 - m) + __expf(a3 - m);
    const float lse = m + __logf(sum);
    lsm[grp] = make_float4(a0 - lse, a1 - lse, a2 - lse, a3 - lse);
  }
  __syncthreads();

  // ---- wave 0, lanes 0..15: gold partial for positions s = j*16 + tid ----
  if (tid < 16) {
    const int s = j * 16 + tid;
    float gp = 0.f; int cp = 0;
    if (words[b * NS + s] != 0) {
      const int t = target[b * NS + s];
      const float4 lv = lsm[tid];
      gp = (t == 0) ? lv.x : (t == 1) ? lv.y : (t == 2) ? lv.z : lv.w;
      if (s > 0) gp += trans[target[b * NS + s - 1] * 4 + t];
      cp = 1;
    }
#pragma unroll
    for (int off = 8; off; off >>= 1) {
      gp += __shfl_xor(gp, off, 16);
      cp += __shfl_xor(cp, off, 16);
    }
    if (tid == 0) { partG[b * 32 + j] = gp; partC[b * 32 + j] = cp; }
    if (tid == 0 && j == 0) l0ws[b] = lsm[0];
  }

  // ---- wave 1, lanes 0..7: chunk recursions (chunks 2j, 2j+1) ----
  if (tid >= 64 && tid < 72) {
    const int k = (tid - 64) >> 2;     // 0,1
    const int a = tid & 3;             // basis row
    const int cg = j * 2 + k;          // global chunk 0..63
    const int s_beg = (cg == 0) ? 1 : cg * 8;
    const int s_end = cg * 8 + 8;

    float T[4][4];
#pragma unroll
    for (int i = 0; i < 4; ++i)
#pragma unroll
      for (int t = 0; t < 4; ++t) T[i][t] = trans[i * 4 + t];

    float v0 = (a == 0) ? 0.f : NEG;
    float v1 = (a == 1) ? 0.f : NEG;
    float v2 = (a == 2) ? 0.f : NEG;
    float v3 = (a == 3) ? 0.f : NEG;
    for (int s = s_beg; s < s_end; ++s) {
      if (words[b * NS + s] != 0) {
        const float4 l = lsm[s - j * 16];
        float t0, t1, t2, t3, m, sm;
        float n0, n1, n2, n3;
        t0 = v0 + T[0][0]; t1 = v1 + T[1][0]; t2 = v2 + T[2][0]; t3 = v3 + T[3][0];
        m = fmaxf(fmaxf(t0, t1), fmaxf(t2, t3));
        sm = __expf(t0 - m) + __expf(t1 - m) + __expf(t2 - m) + __expf(t3 - m);
        n0 = m + __logf(sm) + l.x;
        t0 = v0 + T[0][1]; t1 = v1 + T[1][1]; t2 = v2 + T[2][1]; t3 = v3 + T[3][1];
        m = fmaxf(fmaxf(t0, t1), fmaxf(t2, t3));
        sm = __expf(t0 - m) + __expf(t1 - m) + __expf(t2 - m) + __expf(t3 - m);
        n1 = m + __logf(sm) + l.y;
        t0 = v0 + T[0][2]; t1 = v1 + T[1][2]; t2 = v2 + T[2][2]; t3 = v3 + T[3][2];
        m = fmaxf(fmaxf(t0, t1), fmaxf(t2, t3));
        sm = __expf(t0 - m) + __expf(t1 - m) + __expf(t2 - m) + __expf(t3 - m);
        n2 = m + __logf(sm) + l.z;
        t0 = v0 + T[0][3]; t1 = v1 + T[1][3]; t2 = v2 + T[2][3]; t3 = v3 + T[3][3];
        m = fmaxf(fmaxf(t0, t1), fmaxf(t2, t3));
        sm = __expf(t0 - m) + __expf(t1 - m) + __expf(t2 - m) + __expf(t3 - m);
        n3 = m + __logf(sm) + l.w;
        v0 = n0; v1 = n1; v2 = n2; v3 = n3;
      }
    }
    chunkM[(size_t)(b * 64 + cg) * 4 + a] = make_float4(v0, v1, v2, v3);
  }
}

// ---------------------------------------------------------------------------
// Kernel 2: 6-level tree over 64 chunk matrices + gold finalize. 64 blocks.
// ---------------------------------------------------------------------------
__global__ __launch_bounds__(256) void crf_tree_kernel(
    const int* __restrict__ target, const float* __restrict__ start_s,
    const float* __restrict__ end_s, const float4* __restrict__ chunkM,
    const float* __restrict__ partG, const int* __restrict__ partC,
    const float4* __restrict__ l0ws, float* __restrict__ out)
{
  __shared__ float bufA[64][16];
  __shared__ float bufB[32][16];
  __shared__ float goldS;
  __shared__ int   cntS;

  const int tid = threadIdx.x;
  const int b = blockIdx.x;

  // load chunk matrices (coalesced float4 per thread)
  {
    const int cc = tid >> 2, a = tid & 3;
    const float4 v = chunkM[(size_t)(b * 64 + cc) * 4 + a];
    bufA[cc][a * 4 + 0] = v.x;
    bufA[cc][a * 4 + 1] = v.y;
    bufA[cc][a * 4 + 2] = v.z;
    bufA[cc][a * 4 + 3] = v.w;
  }

  // gold reduce (wave 0, lanes 0..31)
  if (tid < 32) {
    float g = partG[b * 32 + tid];
    int   cp = partC[b * 32 + tid];
#pragma unroll
    for (int off = 16; off; off >>= 1) {
      g  += __shfl_xor(g, off, 32);
      cp += __shfl_xor(cp, off, 32);
    }
    if (tid == 0) { goldS = g; cntS = cp; }
  }

  // 6-level pairwise tree
  float* src = &bufA[0][0];
  float* dst = &bufB[0][0];
  for (int n = 64; n > 1; n >>= 1) {
    const int entries = (n >> 1) * 16;
    __syncthreads();
    for (int e = tid; e < entries; e += 256) {
      const int p = e >> 4;
      const int aa = (e >> 2) & 3;
      const int jj = e & 3;
      const float* C1 = src + (2 * p) * 16;
      const float* C2 = src + (2 * p + 1) * 16;
      const float t0 = C1[aa * 4 + 0] + C2[0 * 4 + jj];
      const float t1 = C1[aa * 4 + 1] + C2[1 * 4 + jj];
      const float t2 = C1[aa * 4 + 2] + C2[2 * 4 + jj];
      const float t3 = C1[aa * 4 + 3] + C2[3 * 4 + jj];
      const float m = fmaxf(fmaxf(t0, t1), fmaxf(t2, t3));
      dst[p * 16 + aa * 4 + jj] =
          m + __logf(__expf(t0 - m) + __expf(t1 - m) +
                     __expf(t2 - m) + __expf(t3 - m));
    }
    float* tmp = src; src = dst; dst = tmp;
  }
  __syncthreads();
  // after 6 swaps the final matrix is back in bufA

  if (tid == 0) {
    const float* C = &bufA[0][0];
    const float4 l0 = l0ws[b];
    const float a0 = l0.x + start_s[0];
    const float a1 = l0.y + start_s[1];
    const float a2 = l0.z + start_s[2];
    const float a3 = l0.w + start_s[3];
    float af[4];
#pragma unroll
    for (int jj = 0; jj < 4; ++jj) {
      const float t0 = a0 + C[0 * 4 + jj];
      const float t1 = a1 + C[1 * 4 + jj];
      const float t2 = a2 + C[2 * 4 + jj];
      const float t3 = a3 + C[3 * 4 + jj];
      const float m = fmaxf(fmaxf(t0, t1), fmaxf(t2, t3));
      af[jj] = m + __logf(__expf(t0 - m) + __expf(t1 - m) +
                          __expf(t2 - m) + __expf(t3 - m));
    }
    const float z0 = af[0] + end_s[0], z1 = af[1] + end_s[1];
    const float z2 = af[2] + end_s[2], z3 = af[3] + end_s[3];
    const float mz = fmaxf(fmaxf(z0, z1), fmaxf(z2, z3));
    const float norm = mz + __logf(__expf(z0 - mz) + __expf(z1 - mz) +
                                   __expf(z2 - mz) + __expf(z3 - mz));

    const int last = (cntS - 1) > 0 ? (cntS - 1) : 0;
    const float gold = goldS + start_s[target[b * NS]] + end_s[target[b * NS + last]];
    out[b] = norm - gold;
  }
}

extern "C" void kernel_launch(void* const* d_in, const int* in_sizes, int n_in,
                              void* d_out, int out_size, void* d_ws, size_t ws_size,
                              hipStream_t stream) {
  const int*   words   = (const int*)d_in[0];
  const int*   target  = (const int*)d_in[1];
  const int*   corpus  = (const int*)d_in[2];
  const float* embed   = (const float*)d_in[3];
  const float* sW      = (const float*)d_in[4];
  const float* sb      = (const float*)d_in[5];
  const float* dA      = (const float*)d_in[6];
  const float* db      = (const float*)d_in[7];
  const float* trans   = (const float*)d_in[8];
  const float* start_s = (const float*)d_in[9];
  const float* end_s   = (const float*)d_in[10];
  float* out = (float*)d_out;

  // ws layout (16B-aligned slabs)
  float4* chunkM = (float4*)d_ws;                         // NB*64*4 float4 = 256 KB
  float4* l0ws   = chunkM + (size_t)NB * 64 * 4;          // NB float4
  float*  partG  = (float*)(l0ws + NB);                   // NB*32 floats
  int*    partC  = (int*)(partG + NB * 32);               // NB*32 ints

  logits_phaseA_kernel<<<NB * 32, 256, 0, stream>>>(
      words, target, corpus, embed, sW, sb, dA, db, trans,
      chunkM, partG, partC, l0ws);
  crf_tree_kernel<<<NB, 256, 0, stream>>>(
      target, start_s, end_s, chunkM, partG, partC, l0ws, out);
}

// Round 11
// 31.820 us; speedup vs baseline: 5.0066x; 1.0586x over previous
//
#include <hip/hip_runtime.h>

#define NB 64
#define NS 512
#define ND 768
#define NT 4
#define NC 10
#define NEG (-1e30f)

// ---------------------------------------------------------------------------
// K1: embedding gather + projection + log_softmax (r5 structure, r9-proven
// conflict-free transposed weights). 2048 blocks x 256 threads; 16 tokens
// per block, 16 lanes per token.
// ---------------------------------------------------------------------------
__global__ __launch_bounds__(256) void logits_kernel(
    const int* __restrict__ words, const int* __restrict__ corpus,
    const float* __restrict__ embed, const float* __restrict__ sW,
    const float* __restrict__ sb, const float* __restrict__ dA,
    const float* __restrict__ db, float* __restrict__ logits)
{
  __shared__ float wt[NT][ND];   // transposed W_eff: wt[t][d]
  __shared__ float4 bl;

  const int tid = threadIdx.x;
  const int blk = blockIdx.x;
  const int b = blk >> 5;                                   // 32 blocks/batch
  const int c = __builtin_amdgcn_readfirstlane(corpus[b]);

  const float4* sW4 = (const float4*)sW;
  const float4* dA4 = ((const float4*)dA) + (size_t)c * ND;
#pragma unroll
  for (int k = 0; k < 3; ++k) {
    const int d = tid + k * 256;
    const float4 a = sW4[d];     // W[d][0..3]
    const float4 e = dA4[d];
    wt[0][d] = a.x + e.x;
    wt[1][d] = a.y + e.y;
    wt[2][d] = a.z + e.z;
    wt[3][d] = a.w + e.w;
  }
  if (tid == 0) {
    const float4 a = *(const float4*)sb;
    const float4 e = ((const float4*)db)[c];
    bl = make_float4(a.x + e.x, a.y + e.y, a.z + e.z, a.w + e.w);
  }
  __syncthreads();

  const int grp = tid >> 4;      // 16 token-groups
  const int q   = tid & 15;
  const int g   = blk * 16 + grp;

  const float4* __restrict__ row4 = (const float4*)(embed + (size_t)words[g] * ND);
  const float4* __restrict__ Wt4 = (const float4*)&wt[0][0];

  float a0 = 0.f, a1 = 0.f, a2 = 0.f, a3 = 0.f;
#pragma unroll
  for (int i = 0; i < 12; ++i) {
    const float4 xv = row4[i * 16 + q];
    const float4 w0 = Wt4[0 * 192 + i * 16 + q];   // banks (q*4)%32 -> 2-way, free
    const float4 w1 = Wt4[1 * 192 + i * 16 + q];
    const float4 w2 = Wt4[2 * 192 + i * 16 + q];
    const float4 w3 = Wt4[3 * 192 + i * 16 + q];
    a0 = fmaf(xv.x, w0.x, a0); a0 = fmaf(xv.y, w0.y, a0);
    a0 = fmaf(xv.z, w0.z, a0); a0 = fmaf(xv.w, w0.w, a0);
    a1 = fmaf(xv.x, w1.x, a1); a1 = fmaf(xv.y, w1.y, a1);
    a1 = fmaf(xv.z, w1.z, a1); a1 = fmaf(xv.w, w1.w, a1);
    a2 = fmaf(xv.x, w2.x, a2); a2 = fmaf(xv.y, w2.y, a2);
    a2 = fmaf(xv.z, w2.z, a2); a2 = fmaf(xv.w, w2.w, a2);
    a3 = fmaf(xv.x, w3.x, a3); a3 = fmaf(xv.y, w3.y, a3);
    a3 = fmaf(xv.z, w3.z, a3); a3 = fmaf(xv.w, w3.w, a3);
  }

#pragma unroll
  for (int off = 8; off; off >>= 1) {
    a0 += __shfl_xor(a0, off);
    a1 += __shfl_xor(a1, off);
    a2 += __shfl_xor(a2, off);
    a3 += __shfl_xor(a3, off);
  }

  if (q == 0) {
    a0 += bl.x; a1 += bl.y; a2 += bl.z; a3 += bl.w;
    const float m = fmaxf(fmaxf(a0, a1), fmaxf(a2, a3));
    const float sum = __expf(a0 - m) + __expf(a1 - m) +
                      __expf(a2 - m) + __expf(a3 - m);
    const float lse = m + __logf(sum);
    ((float4*)logits)[g] = make_float4(a0 - lse, a1 - lse, a2 - lse, a3 - lse);
  }
}

// ---------------------------------------------------------------------------
// K2: CRF phase A (chunk matrices) + gold partials, spread across 128 blocks.
// Block = (batch b, half h): 32 chunks x 4 basis rows = 128 threads.
// Chunk cg covers s in [max(8*cg,1), 8*cg+8). Gold: 2 positions/thread.
// ---------------------------------------------------------------------------
__global__ __launch_bounds__(128) void crf_phaseA_kernel(
    const int* __restrict__ words, const int* __restrict__ target,
    const float* __restrict__ trans, const float* __restrict__ logits,
    float4* __restrict__ chunkM,   // [(b*64+cg)*4 + a]
    float*  __restrict__ partG,    // [NB*2*2]  (b*2+h)*2 + wave
    int*    __restrict__ partC)
{
  const int tid = threadIdx.x;
  const int b = blockIdx.x >> 1;
  const int h = blockIdx.x & 1;

  const float* lg = logits + (size_t)b * NS * NT;
  const int* wb = words + b * NS;
  const int* tb = target + b * NS;

  // ---- gold partial: positions s = h*256 + tid*2 + {0,1} ----
  float gp = 0.f; int cp = 0;
#pragma unroll
  for (int qq = 0; qq < 2; ++qq) {
    const int s = h * 256 + tid * 2 + qq;
    if (wb[s] != 0) {
      const int t = tb[s];
      gp += lg[s * 4 + t];
      if (s > 0) gp += trans[tb[s - 1] * 4 + t];
      ++cp;
    }
  }
#pragma unroll
  for (int off = 32; off; off >>= 1) {
    gp += __shfl_xor(gp, off);
    cp += __shfl_xor(cp, off);
  }
  if ((tid & 63) == 0) {
    partG[(b * 2 + h) * 2 + (tid >> 6)] = gp;
    partC[(b * 2 + h) * 2 + (tid >> 6)] = cp;
  }

  // ---- phase A: chunk cg = h*32 + (tid>>2), basis row a = tid&3 ----
  const int cg = h * 32 + (tid >> 2);
  const int a = tid & 3;
  const int s_beg = (cg == 0) ? 1 : cg * 8;
  const int s_end = cg * 8 + 8;

  float T[4][4];
#pragma unroll
  for (int i = 0; i < 4; ++i)
#pragma unroll
    for (int j = 0; j < 4; ++j) T[i][j] = trans[i * 4 + j];

  float4 lv[8]; int wm[8];
#pragma unroll
  for (int qq = 0; qq < 8; ++qq) {
    const int s = cg * 8 + qq;
    wm[qq] = (s >= s_beg) ? wb[s] : 0;
    lv[qq] = *(const float4*)(lg + s * 4);
  }

  float v0 = (a == 0) ? 0.f : NEG;
  float v1 = (a == 1) ? 0.f : NEG;
  float v2 = (a == 2) ? 0.f : NEG;
  float v3 = (a == 3) ? 0.f : NEG;
#pragma unroll
  for (int qq = 0; qq < 8; ++qq) {
    if (wm[qq] != 0) {
      const float4 l = lv[qq];
      float t0, t1, t2, t3, m, sm;
      float n0, n1, n2, n3;
      t0 = v0 + T[0][0]; t1 = v1 + T[1][0]; t2 = v2 + T[2][0]; t3 = v3 + T[3][0];
      m = fmaxf(fmaxf(t0, t1), fmaxf(t2, t3));
      sm = __expf(t0 - m) + __expf(t1 - m) + __expf(t2 - m) + __expf(t3 - m);
      n0 = m + __logf(sm) + l.x;
      t0 = v0 + T[0][1]; t1 = v1 + T[1][1]; t2 = v2 + T[2][1]; t3 = v3 + T[3][1];
      m = fmaxf(fmaxf(t0, t1), fmaxf(t2, t3));
      sm = __expf(t0 - m) + __expf(t1 - m) + __expf(t2 - m) + __expf(t3 - m);
      n1 = m + __logf(sm) + l.y;
      t0 = v0 + T[0][2]; t1 = v1 + T[1][2]; t2 = v2 + T[2][2]; t3 = v3 + T[3][2];
      m = fmaxf(fmaxf(t0, t1), fmaxf(t2, t3));
      sm = __expf(t0 - m) + __expf(t1 - m) + __expf(t2 - m) + __expf(t3 - m);
      n2 = m + __logf(sm) + l.z;
      t0 = v0 + T[0][3]; t1 = v1 + T[1][3]; t2 = v2 + T[2][3]; t3 = v3 + T[3][3];
      m = fmaxf(fmaxf(t0, t1), fmaxf(t2, t3));
      sm = __expf(t0 - m) + __expf(t1 - m) + __expf(t2 - m) + __expf(t3 - m);
      n3 = m + __logf(sm) + l.w;
      v0 = n0; v1 = n1; v2 = n2; v3 = n3;
    }
  }
  chunkM[(size_t)(b * 64 + cg) * 4 + a] = make_float4(v0, v1, v2, v3);
}

// ---------------------------------------------------------------------------
// K3: 6-level tree over 64 chunk matrices + gold finalize (r10-proven).
// ---------------------------------------------------------------------------
__global__ __launch_bounds__(256) void crf_tree_kernel(
    const int* __restrict__ target, const float* __restrict__ start_s,
    const float* __restrict__ end_s, const float4* __restrict__ chunkM,
    const float* __restrict__ partG, const int* __restrict__ partC,
    const float* __restrict__ logits, float* __restrict__ out)
{
  __shared__ float bufA[64][16];
  __shared__ float bufB[32][16];
  __shared__ float goldS;
  __shared__ int   cntS;

  const int tid = threadIdx.x;
  const int b = blockIdx.x;

  {
    const int cc = tid >> 2, a = tid & 3;
    const float4 v = chunkM[(size_t)(b * 64 + cc) * 4 + a];
    bufA[cc][a * 4 + 0] = v.x;
    bufA[cc][a * 4 + 1] = v.y;
    bufA[cc][a * 4 + 2] = v.z;
    bufA[cc][a * 4 + 3] = v.w;
  }

  if (tid < 4) {
    float g  = partG[b * 4 + tid];
    int   cp = partC[b * 4 + tid];
#pragma unroll
    for (int off = 2; off; off >>= 1) {
      g  += __shfl_xor(g, off, 4);
      cp += __shfl_xor(cp, off, 4);
    }
    if (tid == 0) { goldS = g; cntS = cp; }
  }

  float* src = &bufA[0][0];
  float* dst = &bufB[0][0];
  for (int n = 64; n > 1; n >>= 1) {
    const int entries = (n >> 1) * 16;
    __syncthreads();
    for (int e = tid; e < entries; e += 256) {
      const int p = e >> 4;
      const int aa = (e >> 2) & 3;
      const int jj = e & 3;
      const float* C1 = src + (2 * p) * 16;
      const float* C2 = src + (2 * p + 1) * 16;
      const float t0 = C1[aa * 4 + 0] + C2[0 * 4 + jj];
      const float t1 = C1[aa * 4 + 1] + C2[1 * 4 + jj];
      const float t2 = C1[aa * 4 + 2] + C2[2 * 4 + jj];
      const float t3 = C1[aa * 4 + 3] + C2[3 * 4 + jj];
      const float m = fmaxf(fmaxf(t0, t1), fmaxf(t2, t3));
      dst[p * 16 + aa * 4 + jj] =
          m + __logf(__expf(t0 - m) + __expf(t1 - m) +
                     __expf(t2 - m) + __expf(t3 - m));
    }
    float* tmp = src; src = dst; dst = tmp;
  }
  __syncthreads();

  if (tid == 0) {
    const float* C = &bufA[0][0];
    const float4 l0 = *(const float4*)(logits + (size_t)b * NS * NT);
    const float a0 = l0.x + start_s[0];
    const float a1 = l0.y + start_s[1];
    const float a2 = l0.z + start_s[2];
    const float a3 = l0.w + start_s[3];
    float af[4];
#pragma unroll
    for (int jj = 0; jj < 4; ++jj) {
      const float t0 = a0 + C[0 * 4 + jj];
      const float t1 = a1 + C[1 * 4 + jj];
      const float t2 = a2 + C[2 * 4 + jj];
      const float t3 = a3 + C[3 * 4 + jj];
      const float m = fmaxf(fmaxf(t0, t1), fmaxf(t2, t3));
      af[jj] = m + __logf(__expf(t0 - m) + __expf(t1 - m) +
                          __expf(t2 - m) + __expf(t3 - m));
    }
    const float z0 = af[0] + end_s[0], z1 = af[1] + end_s[1];
    const float z2 = af[2] + end_s[2], z3 = af[3] + end_s[3];
    const float mz = fmaxf(fmaxf(z0, z1), fmaxf(z2, z3));
    const float norm = mz + __logf(__expf(z0 - mz) + __expf(z1 - mz) +
                                   __expf(z2 - mz) + __expf(z3 - mz));

    const int last = (cntS - 1) > 0 ? (cntS - 1) : 0;
    const float gold = goldS + start_s[target[b * NS]] + end_s[target[b * NS + last]];
    out[b] = norm - gold;
  }
}

extern "C" void kernel_launch(void* const* d_in, const int* in_sizes, int n_in,
                              void* d_out, int out_size, void* d_ws, size_t ws_size,
                              hipStream_t stream) {
  const int*   words   = (const int*)d_in[0];
  const int*   target  = (const int*)d_in[1];
  const int*   corpus  = (const int*)d_in[2];
  const float* embed   = (const float*)d_in[3];
  const float* sW      = (const float*)d_in[4];
  const float* sb      = (const float*)d_in[5];
  const float* dA      = (const float*)d_in[6];
  const float* db      = (const float*)d_in[7];
  const float* trans   = (const float*)d_in[8];
  const float* start_s = (const float*)d_in[9];
  const float* end_s   = (const float*)d_in[10];
  float* out = (float*)d_out;

  float*  logits = (float*)d_ws;                          // 512 KB
  float4* chunkM = (float4*)(logits + (size_t)NB * NS * NT);  // 256 KB
  float*  partG  = (float*)(chunkM + (size_t)NB * 64 * 4);    // NB*4 floats
  int*    partC  = (int*)(partG + NB * 4);                    // NB*4 ints

  logits_kernel<<<NB * 32, 256, 0, stream>>>(words, corpus, embed, sW, sb,
                                             dA, db, logits);
  crf_phaseA_kernel<<<NB * 2, 128, 0, stream>>>(words, target, trans, logits,
                                                chunkM, partG, partC);
  crf_tree_kernel<<<NB, 256, 0, stream>>>(target, start_s, end_s, chunkM,
                                          partG, partC, logits, out);
}